// Round 21
// baseline (186.845 us; speedup 1.0000x reference)
//
#include <hip/hip_runtime.h>

constexpr int K_CODES = 512;
constexpr int D_DIM   = 64;
constexpr int HW      = 4096;               // 64*64
constexpr int BATCH   = 32;
constexpr int N_ROWS  = BATCH * HW;         // 131072
constexpr int HALF    = BATCH * D_DIM * HW; // elements per output tensor
constexpr float MU    = 1e-4f;              // 5x over ~2e-5 approx-vs-ref spread

typedef __attribute__((ext_vector_type(8))) short bf16x8;
typedef __attribute__((ext_vector_type(4))) float f32x4;

__device__ __forceinline__ unsigned short f32_bf16_rn(float x) {
    unsigned u = __builtin_bit_cast(unsigned, x);
    unsigned r = (u + 0x7FFFu + ((u >> 16) & 1u)) >> 16;   // round-to-nearest-even
    return (unsigned short)r;
}
__device__ __forceinline__ float bf16_f32(unsigned short h) {
    unsigned u = ((unsigned)h) << 16;
    return __builtin_bit_cast(float, u);
}

// prep: ee[k]=|e_k|^2 (bit-exact sequential f32, = reference), interleaved
// two-term bf16 codebook ehl[k*128 + d]=hi, [.. +64+d]=lo, and transposed
// f32 codebook embT[d*512 + k] (for the coalesced exact slow path).
__global__ void prep(const float* __restrict__ emb, float* __restrict__ ee,
                     unsigned short* __restrict__ ehl, float* __restrict__ embT) {
#pragma clang fp contract(off)
    int k = blockIdx.x * 256 + threadIdx.x;
    if (k >= K_CODES) return;
    const float* w = emb + k * D_DIM;
    float acc = 0.f;
    for (int d = 0; d < D_DIM; ++d) {
        float v = w[d];
        float q = v * v; acc = acc + q;
        unsigned short h = f32_bf16_rn(v);
        ehl[k * 128 + d]      = h;
        ehl[k * 128 + 64 + d] = f32_bf16_rn(v - bf16_f32(h));
        embT[d * K_CODES + k] = v;
    }
    ee[k] = acc;
}

// ======================= PASS 1: half-codebook scan =======================
// Round-15 inner loop VERBATIM, but each block covers 256 codes (64 KB LDS)
// -> 2 blocks/CU co-resident -> 32 waves/CU (2x rounds 14-20's cap, which
// six experiments proved was the plateau). Blocks r and r+256 share rows
// (same XCD: 256%8==0) with complementary code halves. Output: per-row
// (m1, m2, i1) for this half -- 3 MB to d_ws, no 67 MB write tail here.
__global__ __launch_bounds__(1024, 8) void vq_half(const float* __restrict__ zin,
                                                   const float* __restrict__ ee,
                                                   const unsigned short* __restrict__ ehl,
                                                   float* __restrict__ ws_m1,
                                                   float* __restrict__ ws_m2,
                                                   int*   __restrict__ ws_i1) {
#pragma clang fp contract(off)
    __shared__ __attribute__((aligned(16))) short s_cb[256 * 128];  // 64 KB half
    __shared__ __attribute__((aligned(16))) float s_ee[K_CODES];    // 2 KB

    const int tid  = threadIdx.x;
    const int wid  = tid >> 6;           // 0..15
    const int lane = tid & 63;
    const int l15  = lane & 15;
    const int lq   = lane >> 4;          // 0..3 = k-quarter

    const int rb = blockIdx.x & 255;     // row-block
    const int ho = blockIdx.x >> 8;      // code half 0/1
    const int rowbase = rb * 512 + wid * 32;
    const int kbase   = ho * 256;

    // ---- z loads first (f32, 32 per thread); complete under staging.
    // Layout (validated rounds 7-20): col = l15, k = s*32 + lq*8 + j.
    float rz[2][2][8];
#pragma unroll
    for (int rg = 0; rg < 2; ++rg) {
        const int n0 = rowbase + rg * 16 + l15;
        const float* zp = zin + (size_t)(n0 >> 12) * (D_DIM * HW) + (n0 & (HW - 1));
#pragma unroll
        for (int s = 0; s < 2; ++s)
#pragma unroll
            for (int j = 0; j < 8; ++j)
                rz[rg][s][j] = zp[(size_t)(s * 32 + lq * 8 + j) * HW];
    }

    // ---- stage this half's codebook (64 KB), swizzled (math validated
    // rounds 12-20): 4 x 16B per thread.
    const char* src = (const char*)ehl + ho * 65536;
#pragma unroll
    for (int r = 0; r < 4; ++r) {
        const int o = r * (1024 * 16) + tid * 16;     // 0..65520
        const f32x4 v = *(const f32x4*)(src + o);
        const int row = o >> 8;
        const int c16 = (o >> 4) & 15;
        const int so  = (o & ~255) | ((c16 ^ (row & 7)) << 4);
        *(f32x4*)((char*)s_cb + so) = v;
    }
    if (tid < K_CODES) s_ee[tid] = ee[tid];
    __syncthreads();                     // the only barrier

    // ---- convert z to two-term bf16 fragments
    bf16x8 zh[2][2], zl[2][2];
#pragma unroll
    for (int rg = 0; rg < 2; ++rg)
#pragma unroll
        for (int s = 0; s < 2; ++s)
#pragma unroll
            for (int j = 0; j < 8; ++j) {
                const float v = rz[rg][s][j];
                const unsigned short h = f32_bf16_rn(v);
                zh[rg][s][j] = (short)h;
                zl[rg][s][j] = (short)f32_bf16_rn(v - bf16_f32(h));
            }

    // per-lane swizzled fragment byte offsets (row = lct*16+l15, 256 B/row)
    int fb[4];
#pragma unroll
    for (int h = 0; h < 2; ++h)
#pragma unroll
        for (int s = 0; s < 2; ++s)
            fb[h * 2 + s] = l15 * 256 + (((h * 8 + s * 4 + lq) ^ (l15 & 7)) << 4);

    float m1[2] = {3.4e38f, 3.4e38f}, m2[2] = {3.4e38f, 3.4e38f};
    int   i1[2] = {kbase, kbase};

#pragma unroll 4
    for (int lct = 0; lct < 16; ++lct) {
        const char* cb = (const char*)s_cb + lct * 4096;
        const bf16x8 ah0 = *(const bf16x8*)(cb + fb[0]);
        const bf16x8 ah1 = *(const bf16x8*)(cb + fb[1]);
        const bf16x8 al0 = *(const bf16x8*)(cb + fb[2]);
        const bf16x8 al1 = *(const bf16x8*)(cb + fb[3]);
        const f32x4 ev = *(const f32x4*)&s_ee[kbase + lct * 16 + lq * 4];
#pragma unroll
        for (int rg = 0; rg < 2; ++rg) {
            // 3 independent 2-MFMA chains (round 19 proved this ILP is load-bearing)
            f32x4 a0 = {0.f,0.f,0.f,0.f}, a1 = {0.f,0.f,0.f,0.f}, a2 = {0.f,0.f,0.f,0.f};
            a0 = __builtin_amdgcn_mfma_f32_16x16x32_bf16(ah0, zh[rg][0], a0, 0, 0, 0);
            a1 = __builtin_amdgcn_mfma_f32_16x16x32_bf16(al0, zh[rg][0], a1, 0, 0, 0);
            a2 = __builtin_amdgcn_mfma_f32_16x16x32_bf16(ah0, zl[rg][0], a2, 0, 0, 0);
            a0 = __builtin_amdgcn_mfma_f32_16x16x32_bf16(ah1, zh[rg][1], a0, 0, 0, 0);
            a1 = __builtin_amdgcn_mfma_f32_16x16x32_bf16(al1, zh[rg][1], a1, 0, 0, 0);
            a2 = __builtin_amdgcn_mfma_f32_16x16x32_bf16(ah1, zl[rg][1], a2, 0, 0, 0);
#pragma unroll
            for (int r = 0; r < 4; ++r) {
                const float ssum = (a0[r] + a1[r]) + a2[r];
                const float dist = __builtin_fmaf(-2.f, ssum, ev[r]);
                const float hi   = fmaxf(m1[rg], dist);
                m2[rg] = fminf(m2[rg], hi);
                i1[rg] = (dist < m1[rg]) ? (kbase + lct * 16 + lq * 4 + r) : i1[rg];
                m1[rg] = fminf(m1[rg], dist);
            }
        }
    }

    // merge top-2 across the 4 k-quarters (lanes xor 16, 32)
#pragma unroll
    for (int rg = 0; rg < 2; ++rg) {
#pragma unroll
        for (int mk = 16; mk <= 32; mk <<= 1) {
            const float om1 = __shfl_xor(m1[rg], mk, 64);
            const float om2 = __shfl_xor(m2[rg], mk, 64);
            const int   oi  = __shfl_xor(i1[rg], mk, 64);
            const float hi  = fmaxf(m1[rg], om1);
            m2[rg] = fminf(fminf(m2[rg], om2), hi);
            i1[rg] = (om1 < m1[rg]) ? oi : i1[rg];
            m1[rg] = fminf(m1[rg], om1);
        }
    }

    // write per-row half-results (lanes 0-15 hold rows rg*16+l15)
    if (lane < 16) {
#pragma unroll
        for (int rg = 0; rg < 2; ++rg) {
            const int n = rowbase + rg * 16 + l15;
            ws_m1[n * 2 + ho] = m1[rg];
            ws_m2[n * 2 + ho] = m2[rg];
            ws_i1[n * 2 + ho] = i1[rg];
        }
    }
}

// ======================= PASS 2: merge + resolve + write ==================
// Thread per row: exact top-2 lattice merge of the two halves; MU-gap
// certificate; validated wave-cooperative bit-exact slow path for flagged
// rows (~1%); gather + coalesced write of both outputs.
__global__ __launch_bounds__(256) void vq_finish(const float* __restrict__ zin,
                                                 const float* __restrict__ emb,
                                                 const float* __restrict__ ee,
                                                 const float* __restrict__ embT,
                                                 const float* __restrict__ ws_m1,
                                                 const float* __restrict__ ws_m2,
                                                 const int*   __restrict__ ws_i1,
                                                 float* __restrict__ out) {
#pragma clang fp contract(off)
    const int tid  = threadIdx.x;
    const int lane = tid & 63;
    const int n    = blockIdx.x * 256 + tid;

    const float m1a = ws_m1[n * 2],     m2a = ws_m2[n * 2];
    const float m1b = ws_m1[n * 2 + 1], m2b = ws_m2[n * 2 + 1];
    const int   i1a = ws_i1[n * 2],     i1b = ws_i1[n * 2 + 1];

    // exact top-2 merge; tie -> half a (lower code indices) = first occurrence
    float m1, m2; int w;
    if (m1b < m1a) { m1 = m1b; w = i1b; m2 = fminf(m1a, m2b); }
    else           { m1 = m1a; w = i1a; m2 = fminf(m2a, m1b); }

    const bool flagged = (m2 <= m1 + MU);
    unsigned long long fmask = __ballot(flagged);

    if (fmask) {
        // lane L owns codes L*8+j in the exact scan (validated rounds 14-20)
        float ee8[8];
#pragma unroll
        for (int j = 0; j < 8; ++j) ee8[j] = ee[lane * 8 + j];

        while (fmask) {
            const int R = __builtin_ctzll(fmask);
            fmask &= fmask - 1;
            const int nR = (n & ~63) + R;
            const float* zq = zin + (size_t)(nR >> 12) * (D_DIM * HW) + (nR & (HW - 1));

            float zz = 0.f;                         // sequential, separate rounding
            for (int d = 0; d < D_DIM; ++d) {
                const float v = zq[(size_t)d * HW]; // wave-uniform addr -> s_load
                const float q = v * v; zz = zz + q;
            }
            float dot[8];
#pragma unroll
            for (int j = 0; j < 8; ++j) dot[j] = 0.f;
            for (int d = 0; d < D_DIM; ++d) {
                const float zd = zq[(size_t)d * HW];
                const float* er = embT + d * K_CODES + lane * 8;
                const f32x4 e0 = *(const f32x4*)(er);
                const f32x4 e1 = *(const f32x4*)(er + 4);
#pragma unroll
                for (int j = 0; j < 4; ++j) {
                    dot[j]     = __builtin_fmaf(e0[j], zd, dot[j]);
                    dot[j + 4] = __builtin_fmaf(e1[j], zd, dot[j + 4]);
                }
            }
            float bd = 3.4e38f; int bidx = 0;
#pragma unroll
            for (int j = 0; j < 8; ++j) {
                const float mm = 2.0f * dot[j];
                const float s  = zz - mm;
                const float dist = s + ee8[j];
                if (dist < bd) { bd = dist; bidx = lane * 8 + j; }  // strict < : lowest j
            }
#pragma unroll
            for (int mk = 1; mk <= 32; mk <<= 1) {  // lexicographic (dist, idx) min
                const float od = __shfl_xor(bd, mk, 64);
                const int   oi = __shfl_xor(bidx, mk, 64);
                const bool take = (od < bd) || (od == bd && oi < bidx);
                bd   = take ? od : bd;
                bidx = take ? oi : bidx;
            }
            if (lane == R) w = bidx;                // bidx uniform across wave
        }
    }

    // gather + write both outputs; consecutive threads = consecutive rows
    // -> coalesced 1 KB/wave per d
    float* o1 = out + (size_t)(n >> 12) * (D_DIM * HW) + (n & (HW - 1));
    float* o2 = o1 + HALF;
    const float* wv = emb + (size_t)w * D_DIM;
#pragma unroll
    for (int q = 0; q < 16; ++q) {
        const f32x4 v = *(const f32x4*)(wv + q * 4);
#pragma unroll
        for (int i = 0; i < 4; ++i) {
            const int d = q * 4 + i;
            o1[(size_t)d * HW] = v[i];
            o2[(size_t)d * HW] = v[i];
        }
    }
}

// ============== MID TIER: round-15 kernel (proven 65.7 us) ================
__global__ __launch_bounds__(1024, 4) void vq_persist(const float* __restrict__ zin,
                                                      const float* __restrict__ emb,
                                                      const float* __restrict__ ee,
                                                      const unsigned short* __restrict__ ehl,
                                                      const float* __restrict__ embT,
                                                      float* __restrict__ out) {
#pragma clang fp contract(off)
    __shared__ __attribute__((aligned(16))) short s_cb[K_CODES * 128]; // 128 KB
    __shared__ __attribute__((aligned(16))) float s_ee[K_CODES];       // 2 KB

    const int tid  = threadIdx.x;
    const int wid  = tid >> 6;
    const int lane = tid & 63;
    const int l15  = lane & 15;
    const int lq   = lane >> 4;

    const int rowbase = blockIdx.x * 512 + wid * 32;

    float rz[2][2][8];
#pragma unroll
    for (int rg = 0; rg < 2; ++rg) {
        const int n0 = rowbase + rg * 16 + l15;
        const float* zp = zin + (size_t)(n0 >> 12) * (D_DIM * HW) + (n0 & (HW - 1));
#pragma unroll
        for (int s = 0; s < 2; ++s)
#pragma unroll
            for (int j = 0; j < 8; ++j)
                rz[rg][s][j] = zp[(size_t)(s * 32 + lq * 8 + j) * HW];
    }

#pragma unroll
    for (int r = 0; r < 8; ++r) {
        const int o = r * (1024 * 16) + tid * 16;
        const f32x4 v = *(const f32x4*)((const char*)ehl + o);
        const int row = o >> 8;
        const int c16 = (o >> 4) & 15;
        const int so  = (o & ~255) | ((c16 ^ (row & 7)) << 4);
        *(f32x4*)((char*)s_cb + so) = v;
    }
    if (tid < K_CODES) s_ee[tid] = ee[tid];
    __syncthreads();

    bf16x8 zh[2][2], zl[2][2];
#pragma unroll
    for (int rg = 0; rg < 2; ++rg)
#pragma unroll
        for (int s = 0; s < 2; ++s)
#pragma unroll
            for (int j = 0; j < 8; ++j) {
                const float v = rz[rg][s][j];
                const unsigned short h = f32_bf16_rn(v);
                zh[rg][s][j] = (short)h;
                zl[rg][s][j] = (short)f32_bf16_rn(v - bf16_f32(h));
            }

    int fb[4];
#pragma unroll
    for (int h = 0; h < 2; ++h)
#pragma unroll
        for (int s = 0; s < 2; ++s)
            fb[h * 2 + s] = l15 * 256 + (((h * 8 + s * 4 + lq) ^ (l15 & 7)) << 4);

    float m1[2] = {3.4e38f, 3.4e38f}, m2[2] = {3.4e38f, 3.4e38f};
    int   i1[2] = {0, 0};

#pragma unroll 4
    for (int gct = 0; gct < 32; ++gct) {
        const char* cb = (const char*)s_cb + gct * 4096;
        const bf16x8 ah0 = *(const bf16x8*)(cb + fb[0]);
        const bf16x8 ah1 = *(const bf16x8*)(cb + fb[1]);
        const bf16x8 al0 = *(const bf16x8*)(cb + fb[2]);
        const bf16x8 al1 = *(const bf16x8*)(cb + fb[3]);
        const f32x4 ev = *(const f32x4*)&s_ee[gct * 16 + lq * 4];
#pragma unroll
        for (int rg = 0; rg < 2; ++rg) {
            f32x4 a0 = {0.f,0.f,0.f,0.f}, a1 = {0.f,0.f,0.f,0.f}, a2 = {0.f,0.f,0.f,0.f};
            a0 = __builtin_amdgcn_mfma_f32_16x16x32_bf16(ah0, zh[rg][0], a0, 0, 0, 0);
            a1 = __builtin_amdgcn_mfma_f32_16x16x32_bf16(al0, zh[rg][0], a1, 0, 0, 0);
            a2 = __builtin_amdgcn_mfma_f32_16x16x32_bf16(ah0, zl[rg][0], a2, 0, 0, 0);
            a0 = __builtin_amdgcn_mfma_f32_16x16x32_bf16(ah1, zh[rg][1], a0, 0, 0, 0);
            a1 = __builtin_amdgcn_mfma_f32_16x16x32_bf16(al1, zh[rg][1], a1, 0, 0, 0);
            a2 = __builtin_amdgcn_mfma_f32_16x16x32_bf16(ah1, zl[rg][1], a2, 0, 0, 0);
#pragma unroll
            for (int r = 0; r < 4; ++r) {
                const float ssum = (a0[r] + a1[r]) + a2[r];
                const float dist = __builtin_fmaf(-2.f, ssum, ev[r]);
                const float hi   = fmaxf(m1[rg], dist);
                m2[rg] = fminf(m2[rg], hi);
                i1[rg] = (dist < m1[rg]) ? (gct * 16 + lq * 4 + r) : i1[rg];
                m1[rg] = fminf(m1[rg], dist);
            }
        }
    }

#pragma unroll
    for (int rg = 0; rg < 2; ++rg) {
#pragma unroll
        for (int mk = 16; mk <= 32; mk <<= 1) {
            const float om1 = __shfl_xor(m1[rg], mk, 64);
            const float om2 = __shfl_xor(m2[rg], mk, 64);
            const int   oi  = __shfl_xor(i1[rg], mk, 64);
            const float hi  = fmaxf(m1[rg], om1);
            m2[rg] = fminf(fminf(m2[rg], om2), hi);
            i1[rg] = (om1 < m1[rg]) ? oi : i1[rg];
            m1[rg] = fminf(m1[rg], om1);
        }
    }

    int w[2] = {i1[0], i1[1]};

#pragma unroll
    for (int rg = 0; rg < 2; ++rg) {
        const bool flagged = (m2[rg] <= m1[rg] + MU);
        unsigned long long fmask = __ballot(flagged) & 0xFFFFull;
        while (fmask) {
            const int R = __builtin_ctzll(fmask);
            fmask &= fmask - 1;
            const int n = rowbase + rg * 16 + R;
            const float* zq = zin + (size_t)(n >> 12) * (D_DIM * HW) + (n & (HW - 1));
            float zz = 0.f;
            for (int d = 0; d < D_DIM; ++d) {
                const float v = zq[(size_t)d * HW];
                const float q = v * v; zz = zz + q;
            }
            float dot[8];
#pragma unroll
            for (int j = 0; j < 8; ++j) dot[j] = 0.f;
            for (int d = 0; d < D_DIM; ++d) {
                const float zd = zq[(size_t)d * HW];
                const float* er = embT + d * K_CODES + lane * 8;
                const f32x4 e0 = *(const f32x4*)(er);
                const f32x4 e1 = *(const f32x4*)(er + 4);
#pragma unroll
                for (int j = 0; j < 4; ++j) {
                    dot[j]     = __builtin_fmaf(e0[j], zd, dot[j]);
                    dot[j + 4] = __builtin_fmaf(e1[j], zd, dot[j + 4]);
                }
            }
            float bd = 3.4e38f; int bidx = 0;
#pragma unroll
            for (int j = 0; j < 8; ++j) {
                const float mm = 2.0f * dot[j];
                const float s  = zz - mm;
                const float dist = s + s_ee[lane * 8 + j];
                if (dist < bd) { bd = dist; bidx = lane * 8 + j; }
            }
#pragma unroll
            for (int mk = 1; mk <= 32; mk <<= 1) {
                const float od = __shfl_xor(bd, mk, 64);
                const int   oi = __shfl_xor(bidx, mk, 64);
                const bool take = (od < bd) || (od == bd && oi < bidx);
                bd   = take ? od : bd;
                bidx = take ? oi : bidx;
            }
            if ((lane & 15) == R) w[rg] = bidx;
        }
    }

    const int myrow = lane & 31;
    const int win   = w[(lane >> 4) & 1];
    const int n2    = rowbase + myrow;
    const int d0    = (lane >> 5) * 32;
    float* o1 = out + (size_t)(n2 >> 12) * (D_DIM * HW) + (n2 & (HW - 1));
    float* o2 = o1 + HALF;
    const float* wv = emb + (size_t)win * D_DIM + d0;
#pragma unroll
    for (int q = 0; q < 8; ++q) {
        const f32x4 v = *(const f32x4*)(wv + q * 4);
#pragma unroll
        for (int i = 0; i < 4; ++i) {
            const int d = d0 + q * 4 + i;
            o1[(size_t)d * HW] = v[i];
            o2[(size_t)d * HW] = v[i];
        }
    }
}

// fallback (validated round-2 kernel) if ws too small
__global__ __launch_bounds__(256) void vq_fallback(const float* __restrict__ zin,
                                                   const float* __restrict__ emb,
                                                   float* __restrict__ out) {
#pragma clang fp contract(off)
    __shared__ float s_ee[K_CODES];
    const int tid = threadIdx.x;
    for (int k = tid; k < K_CODES; k += 256) {
        const float* w = emb + k * D_DIM;
        float acc = 0.f;
        for (int d = 0; d < D_DIM; ++d) { float q = w[d] * w[d]; acc = acc + q; }
        s_ee[k] = acc;
    }
    __syncthreads();
    const int n = blockIdx.x * 256 + tid;
    const int b = n >> 12;
    const int p = n & (HW - 1);
    const float* zp = zin + (size_t)b * (D_DIM * HW) + p;
    float zr[D_DIM];
#pragma unroll
    for (int d = 0; d < D_DIM; ++d) zr[d] = zp[(size_t)d * HW];
    float zz = 0.f;
#pragma unroll
    for (int d = 0; d < D_DIM; ++d) { float q = zr[d] * zr[d]; zz = zz + q; }
    float best = 3.4e38f; int bi = 0;
    for (int k0 = 0; k0 < K_CODES; k0 += 8) {
        const float* w = emb + (size_t)k0 * D_DIM;
        float dot[8];
#pragma unroll
        for (int j = 0; j < 8; ++j) dot[j] = 0.f;
#pragma unroll
        for (int d = 0; d < D_DIM; ++d) {
            const float z = zr[d];
#pragma unroll
            for (int j = 0; j < 8; ++j)
                dot[j] = __builtin_fmaf(w[j * D_DIM + d], z, dot[j]);
        }
#pragma unroll
        for (int j = 0; j < 8; ++j) {
            const float m = 2.0f * dot[j];
            const float s = zz - m;
            const float dist = s + s_ee[k0 + j];
            if (dist < best) { best = dist; bi = k0 + j; }
        }
    }
    const float* wb = emb + (size_t)bi * D_DIM;
    float* o1 = out + (size_t)b * (D_DIM * HW) + p;
    float* o2 = o1 + HALF;
#pragma unroll
    for (int d = 0; d < D_DIM; ++d) {
        const float v = wb[d];
        o1[(size_t)d * HW] = v;
        o2[(size_t)d * HW] = v;
    }
}

extern "C" void kernel_launch(void* const* d_in, const int* in_sizes, int n_in,
                              void* d_out, int out_size, void* d_ws, size_t ws_size,
                              hipStream_t stream) {
    const float* z   = (const float*)d_in[0];
    const float* emb = (const float*)d_in[1];
    float* out = (float*)d_out;

    const size_t EHL_B  = (size_t)K_CODES * 128 * sizeof(unsigned short); // 128 KB
    const size_t EMBT_B = (size_t)K_CODES * D_DIM * sizeof(float);        // 128 KB
    const size_t base   = 2048 + EHL_B + EMBT_B;                          // 258 KB
    const size_t PERROW = (size_t)N_ROWS * 2 * sizeof(float);             // 1 MB each
    const size_t need_full  = base + 3 * PERROW;                          // ~3.3 MB
    const size_t need_small = base;

    if (ws_size >= need_small) {
        float* ee = (float*)d_ws;
        unsigned short* ehl = (unsigned short*)((char*)d_ws + 2048);
        float* embT = (float*)((char*)d_ws + 2048 + EHL_B);
        hipLaunchKernelGGL(prep, dim3(2), dim3(256), 0, stream, emb, ee, ehl, embT);

        if (ws_size >= need_full) {
            float* ws_m1 = (float*)((char*)d_ws + base);
            float* ws_m2 = (float*)((char*)d_ws + base + PERROW);
            int*   ws_i1 = (int*)  ((char*)d_ws + base + 2 * PERROW);
            hipLaunchKernelGGL(vq_half, dim3(512), dim3(1024), 0, stream,
                               z, ee, ehl, ws_m1, ws_m2, ws_i1);
            hipLaunchKernelGGL(vq_finish, dim3(N_ROWS / 256), dim3(256), 0, stream,
                               z, emb, ee, embT, ws_m1, ws_m2, ws_i1, out);
        } else {
            hipLaunchKernelGGL(vq_persist, dim3(N_ROWS / 512), dim3(1024), 0, stream,
                               z, emb, ee, ehl, embT, out);
        }
    } else {
        hipLaunchKernelGGL(vq_fallback, dim3(N_ROWS / 256), dim3(256), 0, stream,
                           z, emb, out);
    }
}

// Round 22
// 84.535 us; speedup vs baseline: 2.2103x; 2.2103x over previous
//
#include <hip/hip_runtime.h>

constexpr int K_CODES = 512;
constexpr int D_DIM   = 64;
constexpr int HW      = 4096;               // 64*64
constexpr int BATCH   = 32;
constexpr int N_ROWS  = BATCH * HW;         // 131072
constexpr int HALF    = BATCH * D_DIM * HW; // elements per output tensor
constexpr float MU    = 1e-4f;              // 5x over ~2e-5 approx-vs-ref spread

typedef __attribute__((ext_vector_type(8))) short bf16x8;
typedef __attribute__((ext_vector_type(4))) float f32x4;

__device__ __forceinline__ unsigned short f32_bf16_rn(float x) {
    unsigned u = __builtin_bit_cast(unsigned, x);
    unsigned r = (u + 0x7FFFu + ((u >> 16) & 1u)) >> 16;   // round-to-nearest-even
    return (unsigned short)r;
}
__device__ __forceinline__ float bf16_f32(unsigned short h) {
    unsigned u = ((unsigned)h) << 16;
    return __builtin_bit_cast(float, u);
}

// prep: ee[k]=|e_k|^2 (bit-exact sequential f32, = reference), interleaved
// two-term bf16 codebook ehl[k*128 + d]=hi, [.. +64+d]=lo, and transposed
// f32 codebook embT[d*512 + k] (for the coalesced exact slow path).
__global__ void prep(const float* __restrict__ emb, float* __restrict__ ee,
                     unsigned short* __restrict__ ehl, float* __restrict__ embT) {
#pragma clang fp contract(off)
    int k = blockIdx.x * 256 + threadIdx.x;
    if (k >= K_CODES) return;
    const float* w = emb + k * D_DIM;
    float acc = 0.f;
    for (int d = 0; d < D_DIM; ++d) {
        float v = w[d];
        float q = v * v; acc = acc + q;
        unsigned short h = f32_bf16_rn(v);
        ehl[k * 128 + d]      = h;
        ehl[k * 128 + 64 + d] = f32_bf16_rn(v - bf16_f32(h));
        embT[d * K_CODES + k] = v;
    }
    ee[k] = acc;
}

// ======================= PASS 1: half-codebook scan =======================
// ROUND-21 KERNEL with ONE change: __launch_bounds__(1024, 8) -> (1024, 4).
// Round 21's VGPR=32 proved the 64-reg hard cap spilled the ~90-reg live set
// (round-8 failure mode; FETCH 320 MB of scratch traffic). At (1024,4) this
// exact inner loop compiled to spill-free VGPR=64 seven rounds running
// (14-20); VGPR=64 allows 8 waves/SIMD in HW, and 66 KB LDS x 2 < 160 KB,
// so the 2-blocks/CU co-residency round 21 PROVED achievable (occ 73%)
// survives. Blocks rb and rb+256 share rows (same XCD) with complementary
// code halves; output per-row (m1, m2, i1) -- no 67 MB write tail here.
__global__ __launch_bounds__(1024, 4) void vq_half(const float* __restrict__ zin,
                                                   const float* __restrict__ ee,
                                                   const unsigned short* __restrict__ ehl,
                                                   float* __restrict__ ws_m1,
                                                   float* __restrict__ ws_m2,
                                                   int*   __restrict__ ws_i1) {
#pragma clang fp contract(off)
    __shared__ __attribute__((aligned(16))) short s_cb[256 * 128];  // 64 KB half
    __shared__ __attribute__((aligned(16))) float s_ee[K_CODES];    // 2 KB

    const int tid  = threadIdx.x;
    const int wid  = tid >> 6;           // 0..15
    const int lane = tid & 63;
    const int l15  = lane & 15;
    const int lq   = lane >> 4;          // 0..3 = k-quarter

    const int rb = blockIdx.x & 255;     // row-block
    const int ho = blockIdx.x >> 8;      // code half 0/1
    const int rowbase = rb * 512 + wid * 32;
    const int kbase   = ho * 256;

    // ---- z loads first (f32, 32 per thread); complete under staging.
    // Layout (validated rounds 7-21): col = l15, k = s*32 + lq*8 + j.
    float rz[2][2][8];
#pragma unroll
    for (int rg = 0; rg < 2; ++rg) {
        const int n0 = rowbase + rg * 16 + l15;
        const float* zp = zin + (size_t)(n0 >> 12) * (D_DIM * HW) + (n0 & (HW - 1));
#pragma unroll
        for (int s = 0; s < 2; ++s)
#pragma unroll
            for (int j = 0; j < 8; ++j)
                rz[rg][s][j] = zp[(size_t)(s * 32 + lq * 8 + j) * HW];
    }

    // ---- stage this half's codebook (64 KB), swizzled (math validated
    // rounds 12-21): 4 x 16B per thread.
    const char* src = (const char*)ehl + ho * 65536;
#pragma unroll
    for (int r = 0; r < 4; ++r) {
        const int o = r * (1024 * 16) + tid * 16;     // 0..65520
        const f32x4 v = *(const f32x4*)(src + o);
        const int row = o >> 8;
        const int c16 = (o >> 4) & 15;
        const int so  = (o & ~255) | ((c16 ^ (row & 7)) << 4);
        *(f32x4*)((char*)s_cb + so) = v;
    }
    if (tid < K_CODES) s_ee[tid] = ee[tid];
    __syncthreads();                     // the only barrier

    // ---- convert z to two-term bf16 fragments
    bf16x8 zh[2][2], zl[2][2];
#pragma unroll
    for (int rg = 0; rg < 2; ++rg)
#pragma unroll
        for (int s = 0; s < 2; ++s)
#pragma unroll
            for (int j = 0; j < 8; ++j) {
                const float v = rz[rg][s][j];
                const unsigned short h = f32_bf16_rn(v);
                zh[rg][s][j] = (short)h;
                zl[rg][s][j] = (short)f32_bf16_rn(v - bf16_f32(h));
            }

    // per-lane swizzled fragment byte offsets (row = lct*16+l15, 256 B/row)
    int fb[4];
#pragma unroll
    for (int h = 0; h < 2; ++h)
#pragma unroll
        for (int s = 0; s < 2; ++s)
            fb[h * 2 + s] = l15 * 256 + (((h * 8 + s * 4 + lq) ^ (l15 & 7)) << 4);

    float m1[2] = {3.4e38f, 3.4e38f}, m2[2] = {3.4e38f, 3.4e38f};
    int   i1[2] = {kbase, kbase};

#pragma unroll 4
    for (int lct = 0; lct < 16; ++lct) {
        const char* cb = (const char*)s_cb + lct * 4096;
        const bf16x8 ah0 = *(const bf16x8*)(cb + fb[0]);
        const bf16x8 ah1 = *(const bf16x8*)(cb + fb[1]);
        const bf16x8 al0 = *(const bf16x8*)(cb + fb[2]);
        const bf16x8 al1 = *(const bf16x8*)(cb + fb[3]);
        const f32x4 ev = *(const f32x4*)&s_ee[kbase + lct * 16 + lq * 4];
#pragma unroll
        for (int rg = 0; rg < 2; ++rg) {
            // 3 independent 2-MFMA chains (round 19 proved this ILP is load-bearing)
            f32x4 a0 = {0.f,0.f,0.f,0.f}, a1 = {0.f,0.f,0.f,0.f}, a2 = {0.f,0.f,0.f,0.f};
            a0 = __builtin_amdgcn_mfma_f32_16x16x32_bf16(ah0, zh[rg][0], a0, 0, 0, 0);
            a1 = __builtin_amdgcn_mfma_f32_16x16x32_bf16(al0, zh[rg][0], a1, 0, 0, 0);
            a2 = __builtin_amdgcn_mfma_f32_16x16x32_bf16(ah0, zl[rg][0], a2, 0, 0, 0);
            a0 = __builtin_amdgcn_mfma_f32_16x16x32_bf16(ah1, zh[rg][1], a0, 0, 0, 0);
            a1 = __builtin_amdgcn_mfma_f32_16x16x32_bf16(al1, zh[rg][1], a1, 0, 0, 0);
            a2 = __builtin_amdgcn_mfma_f32_16x16x32_bf16(ah1, zl[rg][1], a2, 0, 0, 0);
#pragma unroll
            for (int r = 0; r < 4; ++r) {
                const float ssum = (a0[r] + a1[r]) + a2[r];
                const float dist = __builtin_fmaf(-2.f, ssum, ev[r]);
                const float hi   = fmaxf(m1[rg], dist);
                m2[rg] = fminf(m2[rg], hi);
                i1[rg] = (dist < m1[rg]) ? (kbase + lct * 16 + lq * 4 + r) : i1[rg];
                m1[rg] = fminf(m1[rg], dist);
            }
        }
    }

    // merge top-2 across the 4 k-quarters (lanes xor 16, 32)
#pragma unroll
    for (int rg = 0; rg < 2; ++rg) {
#pragma unroll
        for (int mk = 16; mk <= 32; mk <<= 1) {
            const float om1 = __shfl_xor(m1[rg], mk, 64);
            const float om2 = __shfl_xor(m2[rg], mk, 64);
            const int   oi  = __shfl_xor(i1[rg], mk, 64);
            const float hi  = fmaxf(m1[rg], om1);
            m2[rg] = fminf(fminf(m2[rg], om2), hi);
            i1[rg] = (om1 < m1[rg]) ? oi : i1[rg];
            m1[rg] = fminf(m1[rg], om1);
        }
    }

    // write per-row half-results (lanes 0-15 hold rows rg*16+l15)
    if (lane < 16) {
#pragma unroll
        for (int rg = 0; rg < 2; ++rg) {
            const int n = rowbase + rg * 16 + l15;
            ws_m1[n * 2 + ho] = m1[rg];
            ws_m2[n * 2 + ho] = m2[rg];
            ws_i1[n * 2 + ho] = i1[rg];
        }
    }
}

// ======================= PASS 2: merge + resolve + write ==================
// Thread per row: exact top-2 lattice merge of the two halves; MU-gap
// certificate; validated wave-cooperative bit-exact slow path for flagged
// rows (~1%); gather + coalesced write of both outputs. (Validated round 21,
// absmax 0.0.)
__global__ __launch_bounds__(256) void vq_finish(const float* __restrict__ zin,
                                                 const float* __restrict__ emb,
                                                 const float* __restrict__ ee,
                                                 const float* __restrict__ embT,
                                                 const float* __restrict__ ws_m1,
                                                 const float* __restrict__ ws_m2,
                                                 const int*   __restrict__ ws_i1,
                                                 float* __restrict__ out) {
#pragma clang fp contract(off)
    const int tid  = threadIdx.x;
    const int lane = tid & 63;
    const int n    = blockIdx.x * 256 + tid;

    const float m1a = ws_m1[n * 2],     m2a = ws_m2[n * 2];
    const float m1b = ws_m1[n * 2 + 1], m2b = ws_m2[n * 2 + 1];
    const int   i1a = ws_i1[n * 2],     i1b = ws_i1[n * 2 + 1];

    // exact top-2 merge; tie -> half a (lower code indices) = first occurrence
    float m1, m2; int w;
    if (m1b < m1a) { m1 = m1b; w = i1b; m2 = fminf(m1a, m2b); }
    else           { m1 = m1a; w = i1a; m2 = fminf(m2a, m1b); }

    const bool flagged = (m2 <= m1 + MU);
    unsigned long long fmask = __ballot(flagged);

    if (fmask) {
        // lane L owns codes L*8+j in the exact scan (validated rounds 14-21)
        float ee8[8];
#pragma unroll
        for (int j = 0; j < 8; ++j) ee8[j] = ee[lane * 8 + j];

        while (fmask) {
            const int R = __builtin_ctzll(fmask);
            fmask &= fmask - 1;
            const int nR = (n & ~63) + R;
            const float* zq = zin + (size_t)(nR >> 12) * (D_DIM * HW) + (nR & (HW - 1));

            float zz = 0.f;                         // sequential, separate rounding
            for (int d = 0; d < D_DIM; ++d) {
                const float v = zq[(size_t)d * HW]; // wave-uniform addr -> s_load
                const float q = v * v; zz = zz + q;
            }
            float dot[8];
#pragma unroll
            for (int j = 0; j < 8; ++j) dot[j] = 0.f;
            for (int d = 0; d < D_DIM; ++d) {
                const float zd = zq[(size_t)d * HW];
                const float* er = embT + d * K_CODES + lane * 8;
                const f32x4 e0 = *(const f32x4*)(er);
                const f32x4 e1 = *(const f32x4*)(er + 4);
#pragma unroll
                for (int j = 0; j < 4; ++j) {
                    dot[j]     = __builtin_fmaf(e0[j], zd, dot[j]);
                    dot[j + 4] = __builtin_fmaf(e1[j], zd, dot[j + 4]);
                }
            }
            float bd = 3.4e38f; int bidx = 0;
#pragma unroll
            for (int j = 0; j < 8; ++j) {
                const float mm = 2.0f * dot[j];
                const float s  = zz - mm;
                const float dist = s + ee8[j];
                if (dist < bd) { bd = dist; bidx = lane * 8 + j; }  // strict < : lowest j
            }
#pragma unroll
            for (int mk = 1; mk <= 32; mk <<= 1) {  // lexicographic (dist, idx) min
                const float od = __shfl_xor(bd, mk, 64);
                const int   oi = __shfl_xor(bidx, mk, 64);
                const bool take = (od < bd) || (od == bd && oi < bidx);
                bd   = take ? od : bd;
                bidx = take ? oi : bidx;
            }
            if (lane == R) w = bidx;                // bidx uniform across wave
        }
    }

    // gather + write both outputs; consecutive threads = consecutive rows
    // -> coalesced 1 KB/wave per d
    float* o1 = out + (size_t)(n >> 12) * (D_DIM * HW) + (n & (HW - 1));
    float* o2 = o1 + HALF;
    const float* wv = emb + (size_t)w * D_DIM;
#pragma unroll
    for (int q = 0; q < 16; ++q) {
        const f32x4 v = *(const f32x4*)(wv + q * 4);
#pragma unroll
        for (int i = 0; i < 4; ++i) {
            const int d = q * 4 + i;
            o1[(size_t)d * HW] = v[i];
            o2[(size_t)d * HW] = v[i];
        }
    }
}

// ============== MID TIER: round-15 kernel (proven 65.7 us) ================
__global__ __launch_bounds__(1024, 4) void vq_persist(const float* __restrict__ zin,
                                                      const float* __restrict__ emb,
                                                      const float* __restrict__ ee,
                                                      const unsigned short* __restrict__ ehl,
                                                      const float* __restrict__ embT,
                                                      float* __restrict__ out) {
#pragma clang fp contract(off)
    __shared__ __attribute__((aligned(16))) short s_cb[K_CODES * 128]; // 128 KB
    __shared__ __attribute__((aligned(16))) float s_ee[K_CODES];       // 2 KB

    const int tid  = threadIdx.x;
    const int wid  = tid >> 6;
    const int lane = tid & 63;
    const int l15  = lane & 15;
    const int lq   = lane >> 4;

    const int rowbase = blockIdx.x * 512 + wid * 32;

    float rz[2][2][8];
#pragma unroll
    for (int rg = 0; rg < 2; ++rg) {
        const int n0 = rowbase + rg * 16 + l15;
        const float* zp = zin + (size_t)(n0 >> 12) * (D_DIM * HW) + (n0 & (HW - 1));
#pragma unroll
        for (int s = 0; s < 2; ++s)
#pragma unroll
            for (int j = 0; j < 8; ++j)
                rz[rg][s][j] = zp[(size_t)(s * 32 + lq * 8 + j) * HW];
    }

#pragma unroll
    for (int r = 0; r < 8; ++r) {
        const int o = r * (1024 * 16) + tid * 16;
        const f32x4 v = *(const f32x4*)((const char*)ehl + o);
        const int row = o >> 8;
        const int c16 = (o >> 4) & 15;
        const int so  = (o & ~255) | ((c16 ^ (row & 7)) << 4);
        *(f32x4*)((char*)s_cb + so) = v;
    }
    if (tid < K_CODES) s_ee[tid] = ee[tid];
    __syncthreads();

    bf16x8 zh[2][2], zl[2][2];
#pragma unroll
    for (int rg = 0; rg < 2; ++rg)
#pragma unroll
        for (int s = 0; s < 2; ++s)
#pragma unroll
            for (int j = 0; j < 8; ++j) {
                const float v = rz[rg][s][j];
                const unsigned short h = f32_bf16_rn(v);
                zh[rg][s][j] = (short)h;
                zl[rg][s][j] = (short)f32_bf16_rn(v - bf16_f32(h));
            }

    int fb[4];
#pragma unroll
    for (int h = 0; h < 2; ++h)
#pragma unroll
        for (int s = 0; s < 2; ++s)
            fb[h * 2 + s] = l15 * 256 + (((h * 8 + s * 4 + lq) ^ (l15 & 7)) << 4);

    float m1[2] = {3.4e38f, 3.4e38f}, m2[2] = {3.4e38f, 3.4e38f};
    int   i1[2] = {0, 0};

#pragma unroll 4
    for (int gct = 0; gct < 32; ++gct) {
        const char* cb = (const char*)s_cb + gct * 4096;
        const bf16x8 ah0 = *(const bf16x8*)(cb + fb[0]);
        const bf16x8 ah1 = *(const bf16x8*)(cb + fb[1]);
        const bf16x8 al0 = *(const bf16x8*)(cb + fb[2]);
        const bf16x8 al1 = *(const bf16x8*)(cb + fb[3]);
        const f32x4 ev = *(const f32x4*)&s_ee[gct * 16 + lq * 4];
#pragma unroll
        for (int rg = 0; rg < 2; ++rg) {
            f32x4 a0 = {0.f,0.f,0.f,0.f}, a1 = {0.f,0.f,0.f,0.f}, a2 = {0.f,0.f,0.f,0.f};
            a0 = __builtin_amdgcn_mfma_f32_16x16x32_bf16(ah0, zh[rg][0], a0, 0, 0, 0);
            a1 = __builtin_amdgcn_mfma_f32_16x16x32_bf16(al0, zh[rg][0], a1, 0, 0, 0);
            a2 = __builtin_amdgcn_mfma_f32_16x16x32_bf16(ah0, zl[rg][0], a2, 0, 0, 0);
            a0 = __builtin_amdgcn_mfma_f32_16x16x32_bf16(ah1, zh[rg][1], a0, 0, 0, 0);
            a1 = __builtin_amdgcn_mfma_f32_16x16x32_bf16(al1, zh[rg][1], a1, 0, 0, 0);
            a2 = __builtin_amdgcn_mfma_f32_16x16x32_bf16(ah1, zl[rg][1], a2, 0, 0, 0);
#pragma unroll
            for (int r = 0; r < 4; ++r) {
                const float ssum = (a0[r] + a1[r]) + a2[r];
                const float dist = __builtin_fmaf(-2.f, ssum, ev[r]);
                const float hi   = fmaxf(m1[rg], dist);
                m2[rg] = fminf(m2[rg], hi);
                i1[rg] = (dist < m1[rg]) ? (gct * 16 + lq * 4 + r) : i1[rg];
                m1[rg] = fminf(m1[rg], dist);
            }
        }
    }

#pragma unroll
    for (int rg = 0; rg < 2; ++rg) {
#pragma unroll
        for (int mk = 16; mk <= 32; mk <<= 1) {
            const float om1 = __shfl_xor(m1[rg], mk, 64);
            const float om2 = __shfl_xor(m2[rg], mk, 64);
            const int   oi  = __shfl_xor(i1[rg], mk, 64);
            const float hi  = fmaxf(m1[rg], om1);
            m2[rg] = fminf(fminf(m2[rg], om2), hi);
            i1[rg] = (om1 < m1[rg]) ? oi : i1[rg];
            m1[rg] = fminf(m1[rg], om1);
        }
    }

    int w[2] = {i1[0], i1[1]};

#pragma unroll
    for (int rg = 0; rg < 2; ++rg) {
        const bool flagged = (m2[rg] <= m1[rg] + MU);
        unsigned long long fmask = __ballot(flagged) & 0xFFFFull;
        while (fmask) {
            const int R = __builtin_ctzll(fmask);
            fmask &= fmask - 1;
            const int n = rowbase + rg * 16 + R;
            const float* zq = zin + (size_t)(n >> 12) * (D_DIM * HW) + (n & (HW - 1));
            float zz = 0.f;
            for (int d = 0; d < D_DIM; ++d) {
                const float v = zq[(size_t)d * HW];
                const float q = v * v; zz = zz + q;
            }
            float dot[8];
#pragma unroll
            for (int j = 0; j < 8; ++j) dot[j] = 0.f;
            for (int d = 0; d < D_DIM; ++d) {
                const float zd = zq[(size_t)d * HW];
                const float* er = embT + d * K_CODES + lane * 8;
                const f32x4 e0 = *(const f32x4*)(er);
                const f32x4 e1 = *(const f32x4*)(er + 4);
#pragma unroll
                for (int j = 0; j < 4; ++j) {
                    dot[j]     = __builtin_fmaf(e0[j], zd, dot[j]);
                    dot[j + 4] = __builtin_fmaf(e1[j], zd, dot[j + 4]);
                }
            }
            float bd = 3.4e38f; int bidx = 0;
#pragma unroll
            for (int j = 0; j < 8; ++j) {
                const float mm = 2.0f * dot[j];
                const float s  = zz - mm;
                const float dist = s + s_ee[lane * 8 + j];
                if (dist < bd) { bd = dist; bidx = lane * 8 + j; }
            }
#pragma unroll
            for (int mk = 1; mk <= 32; mk <<= 1) {
                const float od = __shfl_xor(bd, mk, 64);
                const int   oi = __shfl_xor(bidx, mk, 64);
                const bool take = (od < bd) || (od == bd && oi < bidx);
                bd   = take ? od : bd;
                bidx = take ? oi : bidx;
            }
            if ((lane & 15) == R) w[rg] = bidx;
        }
    }

    const int myrow = lane & 31;
    const int win   = w[(lane >> 4) & 1];
    const int n2    = rowbase + myrow;
    const int d0    = (lane >> 5) * 32;
    float* o1 = out + (size_t)(n2 >> 12) * (D_DIM * HW) + (n2 & (HW - 1));
    float* o2 = o1 + HALF;
    const float* wv = emb + (size_t)win * D_DIM + d0;
#pragma unroll
    for (int q = 0; q < 8; ++q) {
        const f32x4 v = *(const f32x4*)(wv + q * 4);
#pragma unroll
        for (int i = 0; i < 4; ++i) {
            const int d = d0 + q * 4 + i;
            o1[(size_t)d * HW] = v[i];
            o2[(size_t)d * HW] = v[i];
        }
    }
}

// fallback (validated round-2 kernel) if ws too small
__global__ __launch_bounds__(256) void vq_fallback(const float* __restrict__ zin,
                                                   const float* __restrict__ emb,
                                                   float* __restrict__ out) {
#pragma clang fp contract(off)
    __shared__ float s_ee[K_CODES];
    const int tid = threadIdx.x;
    for (int k = tid; k < K_CODES; k += 256) {
        const float* w = emb + k * D_DIM;
        float acc = 0.f;
        for (int d = 0; d < D_DIM; ++d) { float q = w[d] * w[d]; acc = acc + q; }
        s_ee[k] = acc;
    }
    __syncthreads();
    const int n = blockIdx.x * 256 + tid;
    const int b = n >> 12;
    const int p = n & (HW - 1);
    const float* zp = zin + (size_t)b * (D_DIM * HW) + p;
    float zr[D_DIM];
#pragma unroll
    for (int d = 0; d < D_DIM; ++d) zr[d] = zp[(size_t)d * HW];
    float zz = 0.f;
#pragma unroll
    for (int d = 0; d < D_DIM; ++d) { float q = zr[d] * zr[d]; zz = zz + q; }
    float best = 3.4e38f; int bi = 0;
    for (int k0 = 0; k0 < K_CODES; k0 += 8) {
        const float* w = emb + (size_t)k0 * D_DIM;
        float dot[8];
#pragma unroll
        for (int j = 0; j < 8; ++j) dot[j] = 0.f;
#pragma unroll
        for (int d = 0; d < D_DIM; ++d) {
            const float z = zr[d];
#pragma unroll
            for (int j = 0; j < 8; ++j)
                dot[j] = __builtin_fmaf(w[j * D_DIM + d], z, dot[j]);
        }
#pragma unroll
        for (int j = 0; j < 8; ++j) {
            const float m = 2.0f * dot[j];
            const float s = zz - m;
            const float dist = s + s_ee[k0 + j];
            if (dist < best) { best = dist; bi = k0 + j; }
        }
    }
    const float* wb = emb + (size_t)bi * D_DIM;
    float* o1 = out + (size_t)b * (D_DIM * HW) + p;
    float* o2 = o1 + HALF;
#pragma unroll
    for (int d = 0; d < D_DIM; ++d) {
        const float v = wb[d];
        o1[(size_t)d * HW] = v;
        o2[(size_t)d * HW] = v;
    }
}

extern "C" void kernel_launch(void* const* d_in, const int* in_sizes, int n_in,
                              void* d_out, int out_size, void* d_ws, size_t ws_size,
                              hipStream_t stream) {
    const float* z   = (const float*)d_in[0];
    const float* emb = (const float*)d_in[1];
    float* out = (float*)d_out;

    const size_t EHL_B  = (size_t)K_CODES * 128 * sizeof(unsigned short); // 128 KB
    const size_t EMBT_B = (size_t)K_CODES * D_DIM * sizeof(float);        // 128 KB
    const size_t base   = 2048 + EHL_B + EMBT_B;                          // 258 KB
    const size_t PERROW = (size_t)N_ROWS * 2 * sizeof(float);             // 1 MB each
    const size_t need_full  = base + 3 * PERROW;                          // ~3.3 MB
    const size_t need_small = base;

    if (ws_size >= need_small) {
        float* ee = (float*)d_ws;
        unsigned short* ehl = (unsigned short*)((char*)d_ws + 2048);
        float* embT = (float*)((char*)d_ws + 2048 + EHL_B);
        hipLaunchKernelGGL(prep, dim3(2), dim3(256), 0, stream, emb, ee, ehl, embT);

        if (ws_size >= need_full) {
            float* ws_m1 = (float*)((char*)d_ws + base);
            float* ws_m2 = (float*)((char*)d_ws + base + PERROW);
            int*   ws_i1 = (int*)  ((char*)d_ws + base + 2 * PERROW);
            hipLaunchKernelGGL(vq_half, dim3(512), dim3(1024), 0, stream,
                               z, ee, ehl, ws_m1, ws_m2, ws_i1);
            hipLaunchKernelGGL(vq_finish, dim3(N_ROWS / 256), dim3(256), 0, stream,
                               z, emb, ee, embT, ws_m1, ws_m2, ws_i1, out);
        } else {
            hipLaunchKernelGGL(vq_persist, dim3(N_ROWS / 512), dim3(1024), 0, stream,
                               z, emb, ee, ehl, embT, out);
        }
    } else {
        hipLaunchKernelGGL(vq_fallback, dim3(N_ROWS / 256), dim3(256), 0, stream,
                           z, emb, out);
    }
}

// Round 23
// 66.892 us; speedup vs baseline: 2.7932x; 1.2638x over previous
//
#include <hip/hip_runtime.h>

constexpr int K_CODES = 512;
constexpr int D_DIM   = 64;
constexpr int HW      = 4096;               // 64*64
constexpr int BATCH   = 32;
constexpr int N_ROWS  = BATCH * HW;         // 131072
constexpr int HALF    = BATCH * D_DIM * HW; // elements per output tensor
constexpr float MU    = 1e-4f;              // 5x over ~2e-5 approx-vs-ref spread
constexpr int TPB     = 1024;               // 16 waves
constexpr int RPB     = 512;                // rows per block (16 waves x 32)

typedef __attribute__((ext_vector_type(8))) short bf16x8;
typedef __attribute__((ext_vector_type(4))) float f32x4;

__device__ __forceinline__ unsigned short f32_bf16_rn(float x) {
    unsigned u = __builtin_bit_cast(unsigned, x);
    unsigned r = (u + 0x7FFFu + ((u >> 16) & 1u)) >> 16;   // round-to-nearest-even
    return (unsigned short)r;
}
__device__ __forceinline__ float bf16_f32(unsigned short h) {
    unsigned u = ((unsigned)h) << 16;
    return __builtin_bit_cast(float, u);
}

// prep: ee[k]=|e_k|^2 (bit-exact sequential f32, = reference), interleaved
// two-term bf16 codebook ehl[k*128 + d]=hi, [.. +64+d]=lo, and transposed
// f32 codebook embT[d*512 + k] (for the coalesced exact slow path).
__global__ void prep(const float* __restrict__ emb, float* __restrict__ ee,
                     unsigned short* __restrict__ ehl, float* __restrict__ embT) {
#pragma clang fp contract(off)
    int k = blockIdx.x * 256 + threadIdx.x;
    if (k >= K_CODES) return;
    const float* w = emb + k * D_DIM;
    float acc = 0.f;
    for (int d = 0; d < D_DIM; ++d) {
        float v = w[d];
        float q = v * v; acc = acc + q;
        unsigned short h = f32_bf16_rn(v);
        ehl[k * 128 + d]      = h;
        ehl[k * 128 + 64 + d] = f32_bf16_rn(v - bf16_f32(h));
        embT[d * K_CODES + k] = v;
    }
    ee[k] = acc;
}

// FINAL KERNEL == ROUND-15 (best validated: 65.7 us bench / 62 us prof,
// absmax 0.0, both validations passed). Locked in after rounds 16-22's seven
// structural experiments (lo-from-global, phase windows, wave de-sync,
// sequential rowgroups, fused MFMA chain, global_load_lds staging, 2-pass
// half-codebook split) all measured neutral or worse.
// Design: persistent whole-codebook-in-LDS block (128 KB, swizzled), 16 waves
// x 32 rows; z loads issued before staging (latency hidden); single-pass
// per-row top-2 via 16x16x32 bf16 MFMA with two-term z/e split in 3
// INDEPENDENT 2-MFMA chains (round 19: this ILP is load-bearing); exact-
// argmin certificate: gap > MU proves approx argmin == reference argmin;
// ambiguous rows (~1%) resolved by a wave-cooperative BIT-EXACT replica of
// the f32 reference pipeline (sequential separate-rounded zz, d-ascending
// fma dot, fl(fl(zz-2dot)+ee), first-occurrence argmin) reading the
// transposed codebook fully coalesced.
__global__ __launch_bounds__(TPB, 4) void vq_persist(const float* __restrict__ zin,
                                                     const float* __restrict__ emb,
                                                     const float* __restrict__ ee,
                                                     const unsigned short* __restrict__ ehl,
                                                     const float* __restrict__ embT,
                                                     float* __restrict__ out) {
#pragma clang fp contract(off)
    __shared__ __attribute__((aligned(16))) short s_cb[K_CODES * 128]; // 128 KB
    __shared__ __attribute__((aligned(16))) float s_ee[K_CODES];       // 2 KB

    const int tid  = threadIdx.x;
    const int wid  = tid >> 6;           // 0..15
    const int lane = tid & 63;
    const int l15  = lane & 15;
    const int lq   = lane >> 4;          // 0..3 = k-quarter

    const int rowbase = blockIdx.x * RPB + wid * 32;

    // ---- issue z loads FIRST (f32, 32 per thread); complete under staging.
    // Layout (validated rounds 7-22): col = l15, k = s*32 + lq*8 + j.
    float rz[2][2][8];
#pragma unroll
    for (int rg = 0; rg < 2; ++rg) {
        const int n0 = rowbase + rg * 16 + l15;
        const float* zp = zin + (size_t)(n0 >> 12) * (D_DIM * HW) + (n0 & (HW - 1));
#pragma unroll
        for (int s = 0; s < 2; ++s)
#pragma unroll
            for (int j = 0; j < 8; ++j)
                rz[rg][s][j] = zp[(size_t)(s * 32 + lq * 8 + j) * HW];
    }

    // ---- stage whole codebook, swizzled: logical byte o (row=o>>8, c16=(o>>4)&15)
    // lands at (o & ~255) | ((c16 ^ (row&7)) << 4). 8 x 16B per thread.
#pragma unroll
    for (int r = 0; r < 8; ++r) {
        const int o = r * (TPB * 16) + tid * 16;
        const f32x4 v = *(const f32x4*)((const char*)ehl + o);
        const int row = o >> 8;
        const int c16 = (o >> 4) & 15;
        const int so  = (o & ~255) | ((c16 ^ (row & 7)) << 4);
        *(f32x4*)((char*)s_cb + so) = v;
    }
    if (tid < K_CODES) s_ee[tid] = ee[tid];
    __syncthreads();                     // the only barrier

    // ---- convert z to two-term bf16 fragments
    bf16x8 zh[2][2], zl[2][2];
#pragma unroll
    for (int rg = 0; rg < 2; ++rg)
#pragma unroll
        for (int s = 0; s < 2; ++s)
#pragma unroll
            for (int j = 0; j < 8; ++j) {
                const float v = rz[rg][s][j];
                const unsigned short h = f32_bf16_rn(v);
                zh[rg][s][j] = (short)h;
                zl[rg][s][j] = (short)f32_bf16_rn(v - bf16_f32(h));
            }

    // per-lane swizzled fragment byte offsets: row = gct*16+l15 (256 B/row),
    // col16 = h*8 + s*4 + lq, swizzled by row&7 = l15&7
    int fb[4];
#pragma unroll
    for (int h = 0; h < 2; ++h)
#pragma unroll
        for (int s = 0; s < 2; ++s)
            fb[h * 2 + s] = l15 * 256 + (((h * 8 + s * 4 + lq) ^ (l15 & 7)) << 4);

    float m1[2] = {3.4e38f, 3.4e38f}, m2[2] = {3.4e38f, 3.4e38f};
    int   i1[2] = {0, 0};

#pragma unroll 4
    for (int gct = 0; gct < 32; ++gct) {
        const char* cb = (const char*)s_cb + gct * 4096;
        const bf16x8 ah0 = *(const bf16x8*)(cb + fb[0]);
        const bf16x8 ah1 = *(const bf16x8*)(cb + fb[1]);
        const bf16x8 al0 = *(const bf16x8*)(cb + fb[2]);
        const bf16x8 al1 = *(const bf16x8*)(cb + fb[3]);
        const f32x4 ev = *(const f32x4*)&s_ee[gct * 16 + lq * 4];
#pragma unroll
        for (int rg = 0; rg < 2; ++rg) {
            // 3 independent 2-MFMA chains: hi*zh, lo*zh, hi*zl
            f32x4 a0 = {0.f,0.f,0.f,0.f}, a1 = {0.f,0.f,0.f,0.f}, a2 = {0.f,0.f,0.f,0.f};
            a0 = __builtin_amdgcn_mfma_f32_16x16x32_bf16(ah0, zh[rg][0], a0, 0, 0, 0);
            a1 = __builtin_amdgcn_mfma_f32_16x16x32_bf16(al0, zh[rg][0], a1, 0, 0, 0);
            a2 = __builtin_amdgcn_mfma_f32_16x16x32_bf16(ah0, zl[rg][0], a2, 0, 0, 0);
            a0 = __builtin_amdgcn_mfma_f32_16x16x32_bf16(ah1, zh[rg][1], a0, 0, 0, 0);
            a1 = __builtin_amdgcn_mfma_f32_16x16x32_bf16(al1, zh[rg][1], a1, 0, 0, 0);
            a2 = __builtin_amdgcn_mfma_f32_16x16x32_bf16(ah1, zl[rg][1], a2, 0, 0, 0);
#pragma unroll
            for (int r = 0; r < 4; ++r) {
                const float ssum = (a0[r] + a1[r]) + a2[r];
                const float dist = __builtin_fmaf(-2.f, ssum, ev[r]);
                const float hi   = fmaxf(m1[rg], dist);
                m2[rg] = fminf(m2[rg], hi);
                i1[rg] = (dist < m1[rg]) ? (gct * 16 + lq * 4 + r) : i1[rg];
                m1[rg] = fminf(m1[rg], dist);
            }
        }
    }

    // merge top-2 across the 4 k-quarters; afterwards every lane holds the
    // final (m1,i1,m2) for row rg*16 + l15
#pragma unroll
    for (int rg = 0; rg < 2; ++rg) {
#pragma unroll
        for (int mk = 16; mk <= 32; mk <<= 1) {
            const float om1 = __shfl_xor(m1[rg], mk, 64);
            const float om2 = __shfl_xor(m2[rg], mk, 64);
            const int   oi  = __shfl_xor(i1[rg], mk, 64);
            const float hi  = fmaxf(m1[rg], om1);
            m2[rg] = fminf(fminf(m2[rg], om2), hi);
            i1[rg] = (om1 < m1[rg]) ? oi : i1[rg];
            m1[rg] = fminf(m1[rg], om1);
        }
    }

    int w[2] = {i1[0], i1[1]};           // winner per (rg, l15), kept in registers

#pragma unroll
    for (int rg = 0; rg < 2; ++rg) {
        const bool flagged = (m2[rg] <= m1[rg] + MU);
        unsigned long long fmask = __ballot(flagged) & 0xFFFFull;

        // slow path: bit-exact full scan for ambiguous rows, wave-cooperative.
        // Lane L owns codes L*8+j; embT reads fully coalesced (f32x4 pairs).
        while (fmask) {
            const int R = __builtin_ctzll(fmask);
            fmask &= fmask - 1;
            const int n = rowbase + rg * 16 + R;
            const float* zq = zin + (size_t)(n >> 12) * (D_DIM * HW) + (n & (HW - 1));

            float zz = 0.f;                         // sequential, separate rounding
            for (int d = 0; d < D_DIM; ++d) {
                const float v = zq[(size_t)d * HW]; // wave-uniform addr -> s_load
                const float q = v * v; zz = zz + q;
            }
            float dot[8];
#pragma unroll
            for (int j = 0; j < 8; ++j) dot[j] = 0.f;
            for (int d = 0; d < D_DIM; ++d) {
                const float zd = zq[(size_t)d * HW];
                const float* er = embT + d * K_CODES + lane * 8;
                const f32x4 e0 = *(const f32x4*)(er);
                const f32x4 e1 = *(const f32x4*)(er + 4);
#pragma unroll
                for (int j = 0; j < 4; ++j) {
                    dot[j]     = __builtin_fmaf(e0[j], zd, dot[j]);
                    dot[j + 4] = __builtin_fmaf(e1[j], zd, dot[j + 4]);
                }
            }
            float bd = 3.4e38f; int bidx = 0;
#pragma unroll
            for (int j = 0; j < 8; ++j) {
                const float mm = 2.0f * dot[j];
                const float s  = zz - mm;
                const float dist = s + s_ee[lane * 8 + j];
                if (dist < bd) { bd = dist; bidx = lane * 8 + j; }  // strict < : lowest j
            }
#pragma unroll
            for (int mk = 1; mk <= 32; mk <<= 1) {  // lexicographic (dist, idx) min
                const float od = __shfl_xor(bd, mk, 64);
                const int   oi = __shfl_xor(bidx, mk, 64);
                const bool take = (od < bd) || (od == bd && oi < bidx);
                bd   = take ? od : bd;
                bidx = take ? oi : bidx;
            }
            if ((lane & 15) == R) w[rg] = bidx;     // bidx uniform across wave
        }
    }

    // ---- epilogue (per-wave, no sync): lane covers row = lane&31 at
    // d-half lane>>5. Winner for that row is in this lane's w[(lane>>4)&1].
    const int myrow = lane & 31;
    const int win   = w[(lane >> 4) & 1];
    const int n2    = rowbase + myrow;
    const int d0    = (lane >> 5) * 32;
    float* o1 = out + (size_t)(n2 >> 12) * (D_DIM * HW) + (n2 & (HW - 1));
    float* o2 = o1 + HALF;
    const float* wv = emb + (size_t)win * D_DIM + d0;
#pragma unroll
    for (int q = 0; q < 8; ++q) {
        const f32x4 v = *(const f32x4*)(wv + q * 4);
#pragma unroll
        for (int i = 0; i < 4; ++i) {
            const int d = d0 + q * 4 + i;
            o1[(size_t)d * HW] = v[i];
            o2[(size_t)d * HW] = v[i];
        }
    }
}

// fallback (validated round-2 kernel) if ws too small
__global__ __launch_bounds__(256) void vq_fallback(const float* __restrict__ zin,
                                                   const float* __restrict__ emb,
                                                   float* __restrict__ out) {
#pragma clang fp contract(off)
    __shared__ float s_ee[K_CODES];
    const int tid = threadIdx.x;
    for (int k = tid; k < K_CODES; k += 256) {
        const float* w = emb + k * D_DIM;
        float acc = 0.f;
        for (int d = 0; d < D_DIM; ++d) { float q = w[d] * w[d]; acc = acc + q; }
        s_ee[k] = acc;
    }
    __syncthreads();
    const int n = blockIdx.x * 256 + tid;
    const int b = n >> 12;
    const int p = n & (HW - 1);
    const float* zp = zin + (size_t)b * (D_DIM * HW) + p;
    float zr[D_DIM];
#pragma unroll
    for (int d = 0; d < D_DIM; ++d) zr[d] = zp[(size_t)d * HW];
    float zz = 0.f;
#pragma unroll
    for (int d = 0; d < D_DIM; ++d) { float q = zr[d] * zr[d]; zz = zz + q; }
    float best = 3.4e38f; int bi = 0;
    for (int k0 = 0; k0 < K_CODES; k0 += 8) {
        const float* w = emb + (size_t)k0 * D_DIM;
        float dot[8];
#pragma unroll
        for (int j = 0; j < 8; ++j) dot[j] = 0.f;
#pragma unroll
        for (int d = 0; d < D_DIM; ++d) {
            const float z = zr[d];
#pragma unroll
            for (int j = 0; j < 8; ++j)
                dot[j] = __builtin_fmaf(w[j * D_DIM + d], z, dot[j]);
        }
#pragma unroll
        for (int j = 0; j < 8; ++j) {
            const float m = 2.0f * dot[j];
            const float s = zz - m;
            const float dist = s + s_ee[k0 + j];
            if (dist < best) { best = dist; bi = k0 + j; }
        }
    }
    const float* wb = emb + (size_t)bi * D_DIM;
    float* o1 = out + (size_t)b * (D_DIM * HW) + p;
    float* o2 = o1 + HALF;
#pragma unroll
    for (int d = 0; d < D_DIM; ++d) {
        const float v = wb[d];
        o1[(size_t)d * HW] = v;
        o2[(size_t)d * HW] = v;
    }
}

extern "C" void kernel_launch(void* const* d_in, const int* in_sizes, int n_in,
                              void* d_out, int out_size, void* d_ws, size_t ws_size,
                              hipStream_t stream) {
    const float* z   = (const float*)d_in[0];
    const float* emb = (const float*)d_in[1];
    float* out = (float*)d_out;

    const size_t EHL_B  = (size_t)K_CODES * 128 * sizeof(unsigned short); // 128 KB
    const size_t EMBT_B = (size_t)K_CODES * D_DIM * sizeof(float);        // 128 KB
    const size_t need = 2048 + EHL_B + EMBT_B;                            // 258 KB
    if (ws_size >= need) {
        float* ee = (float*)d_ws;
        unsigned short* ehl = (unsigned short*)((char*)d_ws + 2048);
        float* embT = (float*)((char*)d_ws + 2048 + EHL_B);
        hipLaunchKernelGGL(prep, dim3(2), dim3(256), 0, stream, emb, ee, ehl, embT);
        hipLaunchKernelGGL(vq_persist, dim3(N_ROWS / RPB), dim3(TPB), 0, stream,
                           z, emb, ee, ehl, embT, out);
    } else {
        hipLaunchKernelGGL(vq_fallback, dim3(N_ROWS / 256), dim3(256), 0, stream,
                           z, emb, out);
    }
}